// Round 2
// baseline (592.481 us; speedup 1.0000x reference)
//
#include <hip/hip_runtime.h>
#include <hip/hip_bf16.h>

#define NUM_LEARNERS 50000
#define NUM_SCENES   2000   // 62 full K-steps of 32 + one tail step of 16
#define EMBED_DIM    128
#define HID          16

typedef __attribute__((ext_vector_type(8))) short bf16x8;  // 8 bf16 in 4 VGPRs
typedef __attribute__((ext_vector_type(4))) float f32x4;

union FragU { unsigned int u[4]; bf16x8 v; };
union BF2U  { __hip_bfloat162 b; unsigned int u; };

// R6: masked-GEMM (one wave = 16 learner rows), same math/layout as R5 which
// passed correctness. Differences vs R5 (theory: R5's float4 ld_lo[4]/ld_hi[4]
// ring indexed by t&3 fell to scratch per rule #20, serializing the K-loop):
//   - prefetch ring = 8 explicitly NAMED float4 variables, zero arrays
//   - __launch_bounds__(64,2): VGPR cap 256 (was 128 -> spill risk); occupancy
//     is grid-limited (~3 waves/SIMD) so the tighter cap bought nothing
//   - bf16 pack via __float22bfloat162_rn intrinsic, not inline asm (m240)
__global__ __launch_bounds__(64, 2) void fused_gather_mean_kernel(
    const float* __restrict__ M,
    const float* __restrict__ W1, const float* __restrict__ b1,
    const float* __restrict__ W2, const float* __restrict__ b2,
    float* __restrict__ out)
{
    const int lane = threadIdx.x & 63;   // one wave per block
    const int r    = lane & 15;          // A-row = h-dim ; B-col = learner-in-tile
    const int g    = lane >> 4;          // k-chunk (8 k's) within a 32-wide K-step
    const int g8   = 8 * g;

    const long row0 = (long)blockIdx.x * 16;           // 3125 blocks, exact
    const float* __restrict__ mrow = M + (row0 + r) * NUM_SCENES;

    const float w1r = W1[r];
    const float b1r = b1[r];

    f32x4 acc_s = {0.f, 0.f, 0.f, 0.f};
    f32x4 acc_c = {0.f, 0.f, 0.f, 0.f};

    FragU ones;                                        // bf16 1.0 pairs
    ones.u[0] = 0x3F803F80u; ones.u[1] = 0x3F803F80u;
    ones.u[2] = 0x3F803F80u; ones.u[3] = 0x3F803F80u;

    // ---- explicit 4-deep prefetch ring: named registers only ----
    float4 lo0, hi0, lo1, hi1, lo2, hi2, lo3, hi3;

    auto ISSUE = [&](int t, float4& lo, float4& hi) {
        int kb = t * 32 + g8;
        kb = (kb > 1992) ? 1992 : kb;   // tail clamp stays in-bounds (cols 1992..1999)
        const float4* p = (const float4*)(mrow + kb);
        lo = p[0];
        hi = p[1];
    };

    auto STEP = [&](int t, const float4& lo, const float4& hi, bool tail) {
        const float va0 = lo.x, va1 = lo.y, va2 = lo.z, va3 = lo.w;
        const float va4 = hi.x, va5 = hi.y, va6 = hi.z, va7 = hi.w;

        // mask fragment: nonzero -> bf16 1.0, packed pairs (elem 2m low, 2m+1 high)
        FragU mf;
        mf.u[0] = ((va0 != 0.0f) ? 0x00003F80u : 0u) | ((va1 != 0.0f) ? 0x3F800000u : 0u);
        mf.u[1] = ((va2 != 0.0f) ? 0x00003F80u : 0u) | ((va3 != 0.0f) ? 0x3F800000u : 0u);
        mf.u[2] = ((va4 != 0.0f) ? 0x00003F80u : 0u) | ((va5 != 0.0f) ? 0x3F800000u : 0u);
        mf.u[3] = ((va6 != 0.0f) ? 0x00003F80u : 0u) | ((va7 != 0.0f) ? 0x3F800000u : 0u);
        if (tail) {  // step 62: only g<2 carry valid k (cols 1984..1999)
            const unsigned int keep = (g < 2) ? 0xFFFFFFFFu : 0u;
            mf.u[0] &= keep; mf.u[1] &= keep; mf.u[2] &= keep; mf.u[3] &= keep;
        }

        // h fragment: relu(k*W1[r]+b1[r]) for k = t*32+8g+j, packed bf16 (RNE)
        const float kb = (float)(t * 32 + g8);
        FragU hf;
#pragma unroll
        for (int m = 0; m < 4; ++m) {
            float h0 = fmaxf(fmaf(kb + (float)(2 * m),     w1r, b1r), 0.0f);
            float h1 = fmaxf(fmaf(kb + (float)(2 * m + 1), w1r, b1r), 0.0f);
            BF2U c; c.b = __float22bfloat162_rn(make_float2(h0, h1));
            hf.u[m] = c.u;
        }

        acc_s = __builtin_amdgcn_mfma_f32_16x16x32_bf16(hf.v,   mf.v, acc_s, 0, 0, 0);
        acc_c = __builtin_amdgcn_mfma_f32_16x16x32_bf16(ones.v, mf.v, acc_c, 0, 0, 0);
    };

    // prologue: fill the ring (steps 0..3)
    ISSUE(0, lo0, hi0); ISSUE(1, lo1, hi1); ISSUE(2, lo2, hi2); ISSUE(3, lo3, hi3);

    // main loop: steps 0..59 in explicit groups of 4 (no dynamic slot index)
    for (int t = 0; t < 60; t += 4) {
        STEP(t + 0, lo0, hi0, false); ISSUE(t + 4, lo0, hi0);
        STEP(t + 1, lo1, hi1, false); ISSUE(t + 5, lo1, hi1);
        STEP(t + 2, lo2, hi2, false); ISSUE(t + 6, lo2, hi2);
        STEP(t + 3, lo3, hi3, false); ISSUE(t + 7, lo3, hi3);
    }
    STEP(60, lo0, hi0, false);
    STEP(61, lo1, hi1, false);
    STEP(62, lo2, hi2, true);    // tail (K=16); ring slot 3 holds clamped dummy

    // ---- epilogue: e[r][d] = (sum_k s[k][r]*W2[k][d] + cnt*b2[d]) / max(cnt,1)
    // acc_s[q] at lane (16g+r) = s[4g+q][r]; gather all 16 k per lane via xor-shfl.
    float sg_[4][4];
#pragma unroll
    for (int q = 0; q < 4; ++q) sg_[0][q] = acc_s[q];                  // k = 4*(g^0)+q
#pragma unroll
    for (int q = 0; q < 4; ++q) sg_[1][q] = __shfl_xor(sg_[0][q], 16); // k = 4*(g^1)+q
#pragma unroll
    for (int q = 0; q < 4; ++q) sg_[2][q] = __shfl_xor(sg_[0][q], 32); // k = 4*(g^2)+q
#pragma unroll
    for (int q = 0; q < 4; ++q) sg_[3][q] = __shfl_xor(sg_[1][q], 32); // k = 4*(g^3)+q

    const float cnt = acc_c[0];                 // exact count[r] (all C-rows equal)
    const float inv = 1.0f / fmaxf(cnt, 1.0f);

    // lane (16g+r) produces out[row0+r][32g .. 32g+31]
    float4 e[8];
    const float4* b2v = (const float4*)(b2 + 32 * g);
#pragma unroll
    for (int u = 0; u < 8; ++u) {
        float4 b = b2v[u];
        e[u].x = cnt * b.x; e[u].y = cnt * b.y;
        e[u].z = cnt * b.z; e[u].w = cnt * b.w;
    }

#pragma unroll
    for (int i = 0; i < 4; ++i) {
        const int kk = 4 * (g ^ i);
#pragma unroll
        for (int q = 0; q < 4; ++q) {
            const float sval = sg_[i][q];
            const float4* w2p = (const float4*)(W2 + (kk + q) * EMBED_DIM + 32 * g);
#pragma unroll
            for (int u = 0; u < 8; ++u) {   // 16 lanes (same g) share addrs -> L1 dedup
                float4 w = w2p[u];
                e[u].x = fmaf(sval, w.x, e[u].x);
                e[u].y = fmaf(sval, w.y, e[u].y);
                e[u].z = fmaf(sval, w.z, e[u].z);
                e[u].w = fmaf(sval, w.w, e[u].w);
            }
        }
    }

    float4* op = (float4*)(out + (row0 + r) * EMBED_DIM + 32 * g);
#pragma unroll
    for (int u = 0; u < 8; ++u) {
        float4 o;
        o.x = e[u].x * inv; o.y = e[u].y * inv;
        o.z = e[u].z * inv; o.w = e[u].w * inv;
        op[u] = o;
    }
}

extern "C" void kernel_launch(void* const* d_in, const int* in_sizes, int n_in,
                              void* d_out, int out_size, void* d_ws, size_t ws_size,
                              hipStream_t stream) {
    const float* M  = (const float*)d_in[0];   // [50000, 2000]
    const float* W1 = (const float*)d_in[1];   // [1, 16]
    const float* b1 = (const float*)d_in[2];   // [16]
    const float* W2 = (const float*)d_in[3];   // [16, 128]
    const float* b2 = (const float*)d_in[4];   // [128]
    float* out = (float*)d_out;                // [50000, 128]

    fused_gather_mean_kernel<<<NUM_LEARNERS / 16, 64, 0, stream>>>(
        M, W1, b1, W2, b2, out);
}

// Round 4
// 523.258 us; speedup vs baseline: 1.1323x; 1.1323x over previous
//
#include <hip/hip_runtime.h>

#define NUM_LEARNERS 50000
#define NUM_SCENES   2000
#define EMBED_DIM    128
#define HID          16

// R8 = R7 resubmitted (previous round failed on container acquisition, not on
// the kernel). R7 = R4 (best measured: 518.9/521.4 us) minus the inter-wave
// barrier.
//
// One wave per learner row. Algebra: sum_{j in nz} mlp[j] =
// W2^T (sum_{j in nz} h(j)) + count*b2, h(j)[k] = relu(j*W1[k]+b1[k]).
//
// Change vs R4: idxbuf is strictly per-wave ([wave][...]), so the
// ds_write -> ds_read ordering is a SAME-WAVE dependency the compiler already
// enforces via s_waitcnt lgkmcnt. The __syncthreads() only coupled the 4
// waves' phase boundaries (every wave stalled on the block's slowest row).
// Removing it decouples the waves for better memory-latency overlap.
__global__ __launch_bounds__(256) void fused_gather_mean_kernel(
    const float* __restrict__ M,
    const float* __restrict__ W1, const float* __restrict__ b1,
    const float* __restrict__ W2, const float* __restrict__ b2,
    float* __restrict__ out)
{
    // 2048-entry rows: phase-2 reads groups of 4 up to index 2047 -> in-bounds.
    __shared__ unsigned short idxbuf[4][2048];         // 16384 B -> 8 blocks/CU
    const int  wave = threadIdx.x >> 6;
    const int  lane = threadIdx.x & 63;
    const long row  = (long)blockIdx.x * 4 + wave;

    const float4* __restrict__ M4 = (const float4*)(M + row * NUM_SCENES); // 8000B row
    unsigned short* myidx = idxbuf[wave];

    // ---- Phase 0: prefetch the full row first (8 independent dwordx4 loads)
    float4 v[8];
#pragma unroll
    for (int it = 0; it < 8; ++it) {
        int c4 = it * 64 + lane;                 // < 448 for it<7 (no branch)
        if (c4 < 500) v[it] = M4[c4];
        else          v[it] = make_float4(0.f, 0.f, 0.f, 0.f);
    }

    // Lane roles for phase 2: group g = lane>>2 consumes 4 consecutive
    // indices per iteration; sub = lane&3 covers h-dims 4*sub..4*sub+3.
    const int g   = lane >> 2;
    const int sub = lane & 3;
    float w1v[4], b1v[4];
#pragma unroll
    for (int c = 0; c < 4; ++c) {
        w1v[c] = W1[4 * sub + c];
        b1v[c] = b1[4 * sub + c];
    }

    // ---- Phase 1: ballot-compaction of nonzero column indices ----
    int count = 0;
#pragma unroll
    for (int it = 0; it < 8; ++it) {
        int c4 = it * 64 + lane;
        float vals[4] = {v[it].x, v[it].y, v[it].z, v[it].w};
#pragma unroll
        for (int c = 0; c < 4; ++c) {
            bool nz = (vals[c] != 0.0f);
            unsigned long long m = __ballot(nz);
            if (nz) {
                int below = __builtin_amdgcn_mbcnt_hi(
                    (unsigned)(m >> 32),
                    __builtin_amdgcn_mbcnt_lo((unsigned)m, 0));
                myidx[count + below] = (unsigned short)(c4 * 4 + c);
            }
            count += __popcll(m);                // wave-uniform running total
        }
    }

    // NO __syncthreads() here: same-wave ds_write->ds_read ordering is
    // enforced by compiler-inserted s_waitcnt lgkmcnt; no cross-wave sharing.

    // ---- Phase 2: in-register h-sum, 64 indices per iteration ----
    float4 acc = make_float4(0.f, 0.f, 0.f, 0.f);
    const int nIter = (count + 63) >> 6;
    for (int t = 0; t < nIter; ++t) {
        int base = t * 64 + g * 4;               // group's 4 indices
        ushort4 idx4 = *(const ushort4*)&myidx[base];  // ds_read_b64, bcast in group
        const unsigned short* iq = (const unsigned short*)&idx4;
#pragma unroll
        for (int q = 0; q < 4; ++q) {
            float x    = (float)iq[q];
            float mval = (base + q < count) ? 1.0f : 0.0f;   // tail mask
#pragma unroll
            for (int c = 0; c < 4; ++c) {
                float h = fmaxf(fmaf(x, w1v[c], b1v[c]), 0.0f);
                (&acc.x)[c] = fmaf(h, mval, (&acc.x)[c]);
            }
        }
    }

    // Reduce across the 16 index-groups: butterfly over strides 4,8,16,32.
#pragma unroll
    for (int off = 4; off < 64; off <<= 1) {
        acc.x += __shfl_xor(acc.x, off);
        acc.y += __shfl_xor(acc.y, off);
        acc.z += __shfl_xor(acc.z, off);
        acc.w += __shfl_xor(acc.w, off);
    }
    // Lane l holds s[4*(l&3)+c]; broadcast all 16 to every lane.
    float s[HID];
#pragma unroll
    for (int a = 0; a < 4; ++a) {
        s[4 * a + 0] = __shfl(acc.x, a);
        s[4 * a + 1] = __shfl(acc.y, a);
        s[4 * a + 2] = __shfl(acc.z, a);
        s[4 * a + 3] = __shfl(acc.w, a);
    }

    // ---- Epilogue: emb[d] = (sum_k s[k]*W2[k][d] + count*b2[d]) / max(count,1)
    // Lane l owns dims 2l, 2l+1. W2 (8KB) / b2 (512B) are L1-hot.
    const float cnt = (float)count;
    const float inv = 1.0f / fmaxf(cnt, 1.0f);
    const float2* __restrict__ W2v = (const float2*)W2;    // [16][64] float2
    float2 bv = ((const float2*)b2)[lane];
    float e0 = cnt * bv.x;
    float e1 = cnt * bv.y;
#pragma unroll
    for (int k = 0; k < HID; ++k) {
        float2 w = W2v[k * 64 + lane];
        e0 = fmaf(s[k], w.x, e0);
        e1 = fmaf(s[k], w.y, e1);
    }
    ((float2*)out)[row * 64 + lane] = make_float2(e0 * inv, e1 * inv);
}

extern "C" void kernel_launch(void* const* d_in, const int* in_sizes, int n_in,
                              void* d_out, int out_size, void* d_ws, size_t ws_size,
                              hipStream_t stream) {
    const float* M  = (const float*)d_in[0];   // [50000, 2000]
    const float* W1 = (const float*)d_in[1];   // [1, 16]
    const float* b1 = (const float*)d_in[2];   // [16]
    const float* W2 = (const float*)d_in[3];   // [16, 128]
    const float* b2 = (const float*)d_in[4];   // [128]
    float* out = (float*)d_out;                // [50000, 128]

    fused_gather_mean_kernel<<<NUM_LEARNERS / 4, 256, 0, stream>>>(
        M, W1, b1, W2, b2, out);
}